// Round 10
// baseline (34.802 us; speedup 1.0000x reference)
//
#include <hip/hip_runtime.h>

#define PAD 2
#define PX 4                  // pixels per lane along x
#define WROWS 4               // output rows per tile
#define NT 2                  // tiles per wave (pipelined)
#define TSX 64                // output cols per tile
#define LTW 68                // halo tile width (floats)
#define LTH (WROWS + 2 * PAD) // 8 halo rows
#define SLICE (LTH * LTW)     // 544 floats per tile buffer
#define NCHUNK (SLICE / 4)    // 136 float4 chunks

typedef float v4f __attribute__((ext_vector_type(4)));

typedef __attribute__((address_space(1))) const void ga_void;
typedef __attribute__((address_space(3))) void ls_void;

__device__ __forceinline__ float min3f(float a, float b, float c) {
    return fminf(fminf(a, b), c);
}
__device__ __forceinline__ float max3f(float a, float b, float c) {
    return fmaxf(fmaxf(a, b), c);
}
__device__ __forceinline__ float med3f(float a, float b, float c) {
    return fmaxf(fminf(a, b), fminf(fmaxf(a, b), c));
}

#define CE(a, b) { float _lo = fminf(a, b), _hi = fmaxf(a, b); (a) = _lo; (b) = _hi; }

// median of 9 in q4 (Devillard 19-CE network)
#define MED9(q0, q1, q2, q3, q4, q5, q6, q7, q8) \
    CE(q1, q2) CE(q4, q5) CE(q7, q8) \
    CE(q0, q1) CE(q3, q4) CE(q6, q7) \
    CE(q1, q2) CE(q4, q5) CE(q7, q8) \
    CE(q0, q3) CE(q5, q8) CE(q4, q7) \
    CE(q3, q6) CE(q1, q4) CE(q2, q5) \
    CE(q4, q7) CE(q4, q2) CE(q6, q4) \
    CE(q4, q2)

__global__ __launch_bounds__(64, 4) void denoise_median5_kernel(
    const float* __restrict__ x,
    const float* __restrict__ noise_var_p,
    const float* __restrict__ noise_bias_p,
    float* __restrict__ out,
    int H, int W)
{
    __shared__ float lds[NT * SLICE];   // 4352 B: two tile buffers

    const float noise_var  = noise_var_p[0];
    const float noise_bias = noise_bias_p[0];

    const int lane = threadIdx.x;
    const int b      = blockIdx.z;
    const int tile_x = blockIdx.x * TSX;
    const int wy0    = blockIdx.y * (WROWS * NT);   // first tile's first output row
    const int wy1    = wy0 + WROWS;
    const int gx0    = tile_x - PAD;

    const float* __restrict__ img = x + (size_t)b * H * W;
    float* __restrict__ buf0 = &lds[0];
    float* __restrict__ buf1 = &lds[SLICE];

    const bool okx  = (blockIdx.x >= 1) && (blockIdx.x <= gridDim.x - 2);
    const bool int0 = okx && (wy0 >= PAD) && (wy0 <= H - LTH + PAD);
    const bool int1 = okx && (wy1 >= PAD) && (wy1 <= H - LTH + PAD);

    // ---------------- STAGE tile0 ----------------
    if (int0) {
        const float* gbase = img + (size_t)(wy0 - PAD) * W + gx0;
        #pragma unroll
        for (int batch = 0; batch < 2; ++batch) {
            const int chunk = batch * 64 + lane;
            const int row = chunk / 17;
            const int cc  = chunk - row * 17;
            __builtin_amdgcn_global_load_lds((ga_void*)(gbase + (size_t)row * W + cc * 4),
                                             (ls_void*)(buf0 + batch * 256), 16, 0, 0);
        }
        if (lane < NCHUNK - 128) {
            const int chunk = 128 + lane;
            const int row = chunk / 17;
            const int cc  = chunk - row * 17;
            __builtin_amdgcn_global_load_lds((ga_void*)(gbase + (size_t)row * W + cc * 4),
                                             (ls_void*)(buf0 + 512), 16, 0, 0);
        }
    } else {
        for (int i = lane; i < SLICE; i += 64) {
            const int ly = i / LTW;
            const int lx = i - ly * LTW;
            const int gy = wy0 - PAD + ly;
            const int gx = gx0 + lx;
            float v = 0.0f;
            if ((unsigned)gy < (unsigned)H && (unsigned)gx < (unsigned)W)
                v = img[(size_t)gy * W + gx];
            buf0[i] = v;
        }
    }

    // ---------------- STAGE tile1 ----------------
    if (int1) {
        const float* gbase = img + (size_t)(wy1 - PAD) * W + gx0;
        #pragma unroll
        for (int batch = 0; batch < 2; ++batch) {
            const int chunk = batch * 64 + lane;
            const int row = chunk / 17;
            const int cc  = chunk - row * 17;
            __builtin_amdgcn_global_load_lds((ga_void*)(gbase + (size_t)row * W + cc * 4),
                                             (ls_void*)(buf1 + batch * 256), 16, 0, 0);
        }
        if (lane < NCHUNK - 128) {
            const int chunk = 128 + lane;
            const int row = chunk / 17;
            const int cc  = chunk - row * 17;
            __builtin_amdgcn_global_load_lds((ga_void*)(gbase + (size_t)row * W + cc * 4),
                                             (ls_void*)(buf1 + 512), 16, 0, 0);
        }
    } else {
        for (int i = lane; i < SLICE; i += 64) {
            const int ly = i / LTW;
            const int lx = i - ly * LTW;
            const int gy = wy1 - PAD + ly;
            const int gx = gx0 + lx;
            float v = 0.0f;
            if ((unsigned)gy < (unsigned)H && (unsigned)gx < (unsigned)W)
                v = img[(size_t)gy * W + gx];
            buf1[i] = v;
        }
    }

    const int lx16 = lane & 15;
    const int lrow = lane >> 4;

    // One tile: read 5 rows from ldsbase, compute 4 px, store.
    auto compute_tile = [&](const float* __restrict__ ldsbase, int wy) {
        v4f A[5], Dq[5];
        #pragma unroll
        for (int r = 0; r < 5; ++r) {
            A[r]  = *(const v4f*)&ldsbase[(lrow + r) * LTW + lx16 * 4];
            Dq[r] = *(const v4f*)&ldsbase[(lrow + r) * LTW + lx16 * 4 + 4];
        }

        v4f SA = ((A[0] + A[1]) + (A[2] + A[3])) + A[4];
        v4f SD = ((Dq[0] + Dq[1]) + (Dq[2] + Dq[3])) + Dq[4];
        v4f QA = A[0] * A[0];
        v4f QD = Dq[0] * Dq[0];
        #pragma unroll
        for (int r = 1; r < 5; ++r) { QA = A[r] * A[r] + QA; QD = Dq[r] * Dq[r] + QD; }

        const float s8[8] = {SA.x, SA.y, SA.z, SA.w, SD.x, SD.y, SD.z, SD.w};
        const float q8[8] = {QA.x, QA.y, QA.z, QA.w, QD.x, QD.y, QD.z, QD.w};

        float sum5[PX], sq5[PX];
        sum5[0] = ((s8[0] + s8[1]) + (s8[2] + s8[3])) + s8[4];
        sq5[0]  = ((q8[0] + q8[1]) + (q8[2] + q8[3])) + q8[4];
        #pragma unroll
        for (int p = 1; p < PX; ++p) {
            sum5[p] = sum5[p - 1] - s8[p - 1] + s8[p + 4];
            sq5[p]  = sq5[p - 1]  - q8[p - 1] + q8[p + 4];
        }

        const float center[PX] = {A[2].z, A[2].w, Dq[2].x, Dq[2].y};

        float c[8][5];
        #pragma unroll
        for (int r = 0; r < 5; ++r) {
            c[0][r] = A[r].x;  c[1][r] = A[r].y;  c[2][r] = A[r].z;  c[3][r] = A[r].w;
            c[4][r] = Dq[r].x; c[5][r] = Dq[r].y; c[6][r] = Dq[r].z; c[7][r] = Dq[r].w;
        }
        #pragma unroll
        for (int k = 0; k < 8; ++k) {
            const float a1 = fminf(c[k][0], c[k][1]), a2 = fmaxf(c[k][0], c[k][1]);
            const float b1 = fminf(c[k][2], c[k][3]), b2 = fmaxf(c[k][2], c[k][3]);
            const float cc = c[k][4];
            const float t1 = fminf(a2, b2), t3 = fmaxf(a1, b1);
            const float M  = fmaxf(a2, b2), m  = fminf(a1, b1);
            c[k][0] = fminf(m, cc);
            c[k][4] = fmaxf(M, cc);
            c[k][2] = med3f(t1, t3, cc);
            c[k][3] = max3f(t1, fminf(cc, M), t3);
            c[k][1] = min3f(t3, fmaxf(cc, m), t1);
        }

        float4 res;
        float* resp = (float*)&res;

        #pragma unroll
        for (int p = 0; p < PX; ++p) {
            float A1, A2, B1, B2, B3, C1, C2, C3, D1, D2, D3, E1, E2;
            {
                const float a1 = fminf(c[p][0], c[p+1][0]), a2 = fmaxf(c[p][0], c[p+1][0]);
                const float b1 = fminf(c[p+2][0], c[p+3][0]), b2 = fmaxf(c[p+2][0], c[p+3][0]);
                const float cc = c[p+4][0];
                const float M = fmaxf(a2, b2), t1 = fminf(a2, b2), t3 = fmaxf(a1, b1);
                A2 = fmaxf(M, cc);
                A1 = max3f(t1, fminf(cc, M), t3);
            }
            {
                const float a1 = fminf(c[p][1], c[p+1][1]), a2 = fmaxf(c[p][1], c[p+1][1]);
                const float b1 = fminf(c[p+2][1], c[p+3][1]), b2 = fmaxf(c[p+2][1], c[p+3][1]);
                const float cc = c[p+4][1];
                const float M = fmaxf(a2, b2), t1 = fminf(a2, b2), t3 = fmaxf(a1, b1);
                B3 = fmaxf(M, cc);
                B2 = max3f(t1, fminf(cc, M), t3);
                B1 = med3f(t1, t3, cc);
            }
            {
                const float a1 = fminf(c[p][2], c[p+1][2]), a2 = fmaxf(c[p][2], c[p+1][2]);
                const float b1 = fminf(c[p+2][2], c[p+3][2]), b2 = fmaxf(c[p+2][2], c[p+3][2]);
                const float cc = c[p+4][2];
                const float M = fmaxf(a2, b2), m = fminf(a1, b1);
                const float t1 = fminf(a2, b2), t3 = fmaxf(a1, b1);
                C2 = med3f(t1, t3, cc);
                C3 = max3f(t1, fminf(cc, M), t3);
                C1 = min3f(t3, fmaxf(cc, m), t1);
            }
            {
                const float a1 = fminf(c[p][3], c[p+1][3]), a2 = fmaxf(c[p][3], c[p+1][3]);
                const float b1 = fminf(c[p+2][3], c[p+3][3]), b2 = fmaxf(c[p+2][3], c[p+3][3]);
                const float cc = c[p+4][3];
                const float m = fminf(a1, b1), t1 = fminf(a2, b2), t3 = fmaxf(a1, b1);
                D1 = fminf(m, cc);
                D2 = min3f(t3, fmaxf(cc, m), t1);
                D3 = med3f(t1, t3, cc);
            }
            {
                const float a1 = fminf(c[p][4], c[p+1][4]), a2 = fmaxf(c[p][4], c[p+1][4]);
                const float b1 = fminf(c[p+2][4], c[p+3][4]), b2 = fmaxf(c[p+2][4], c[p+3][4]);
                const float cc = c[p+4][4];
                const float m = fminf(a1, b1), t1 = fminf(a2, b2), t3 = fmaxf(a1, b1);
                E1 = fminf(m, cc);
                E2 = min3f(t3, fmaxf(cc, m), t1);
            }

            const float mn1 = fminf(B3, D3);
            const float mn2 = fminf(C3, E2);
            const float mx1 = fmaxf(B1, D1);
            const float mx2 = fmaxf(A1, C1);

            float q0 = mx2, q1 = A2, q2 = B2, q3 = C2, q4 = D2,
                  q5 = E1, q6 = mx1, q7 = mn1, q8 = mn2;
            MED9(q0, q1, q2, q3, q4, q5, q6, q7, q8);
            const float mid = q4;

            const float sum = sum5[p];
            const float sq  = sq5[p];
            const float mean = sum * (1.0f / 25.0f);
            float var = (sq - sum * mean) * (1.0f / 24.0f);
            var = fmaxf(var, 0.0f);

            const float xc = center[p];
            const float rr = __builtin_amdgcn_rcpf(var + 1e-10f);
            float y = xc - noise_var * rr * (xc - mid + noise_bias);
            resp[p] = fmaxf(y, 0.0f);
        }

        const int orow = wy + lrow;
        const int ox   = tile_x + lx16 * PX;
        *(float4*)&out[((size_t)b * H + orow) * W + ox] = res;
    };

    // ---- wait for buf0 only (tile1's loads stay in flight), compute tile0 ----
    if (int0 && int1) {
        asm volatile("s_waitcnt vmcnt(3)" ::: "memory");
    } else {
        asm volatile("s_waitcnt vmcnt(0) lgkmcnt(0)" ::: "memory");
    }
    __builtin_amdgcn_sched_barrier(0);
    compute_tile(buf0, wy0);

    // ---- wait for buf1 (vmcnt(1) excludes the tile0 store just issued) ----
    if (int1) {
        asm volatile("s_waitcnt vmcnt(1) lgkmcnt(0)" ::: "memory");
    } else {
        asm volatile("s_waitcnt lgkmcnt(0)" ::: "memory");
    }
    __builtin_amdgcn_sched_barrier(0);
    compute_tile(buf1, wy1);
}

extern "C" void kernel_launch(void* const* d_in, const int* in_sizes, int n_in,
                              void* d_out, int out_size, void* d_ws, size_t ws_size,
                              hipStream_t stream)
{
    const float* x  = (const float*)d_in[0];
    const float* nv = (const float*)d_in[1];
    const float* nb = (const float*)d_in[2];
    float* out = (float*)d_out;

    const int H = 512, W = 512;
    const int B = in_sizes[0] / (H * W);   // 16 (C==1)

    dim3 block(64, 1, 1);
    dim3 grid(W / TSX, H / (WROWS * NT), B);   // (8, 64, 16) = 8192 single-wave blocks
    denoise_median5_kernel<<<grid, block, 0, stream>>>(x, nv, nb, out, H, W);
}

// Round 11
// 31.663 us; speedup vs baseline: 1.0992x; 1.0992x over previous
//
#include <hip/hip_runtime.h>

#define PAD 2
#define PX 4                 // pixels per thread along x
#define BDX 16
#define BDY 16
#define TSX (BDX * PX)       // 64 outputs wide per block
#define TSY BDY              // 16 outputs high per block
#define LTW (TSX + 2 * PAD)  // 68 (= 17 float4 chunks)
#define LTH (TSY + 2 * PAD)  // 20
#define NCHUNK (LTH * LTW / 4)  // 340

// 16B vector with only 4B alignment guarantee (global loads at -2 offset)
typedef float float4u __attribute__((vector_size(16), aligned(4)));
typedef float v4f __attribute__((ext_vector_type(4)));

__device__ __forceinline__ float min3f(float a, float b, float c) {
    float r; asm("v_min3_f32 %0, %1, %2, %3" : "=v"(r) : "v"(a), "v"(b), "v"(c)); return r;
}
__device__ __forceinline__ float max3f(float a, float b, float c) {
    float r; asm("v_max3_f32 %0, %1, %2, %3" : "=v"(r) : "v"(a), "v"(b), "v"(c)); return r;
}
__device__ __forceinline__ float med3f(float a, float b, float c) {
    float r; asm("v_med3_f32 %0, %1, %2, %3" : "=v"(r) : "v"(a), "v"(b), "v"(c)); return r;
}

// compare-exchange (for MED9 network; dead halves are DCE'd)
#define CE(a, b) { float _lo = fminf(a, b), _hi = fmaxf(a, b); (a) = _lo; (b) = _hi; }

// median of 9 in q4 (Devillard 19-CE network; ~30 ops after DCE)
#define MED9(q0, q1, q2, q3, q4, q5, q6, q7, q8) \
    CE(q1, q2) CE(q4, q5) CE(q7, q8) \
    CE(q0, q1) CE(q3, q4) CE(q6, q7) \
    CE(q1, q2) CE(q4, q5) CE(q7, q8) \
    CE(q0, q3) CE(q5, q8) CE(q4, q7) \
    CE(q3, q6) CE(q1, q4) CE(q2, q5) \
    CE(q4, q7) CE(q4, q2) CE(q6, q4) \
    CE(q4, q2)

__global__ __launch_bounds__(256) void denoise_median5_kernel(
    const float* __restrict__ x,
    const float* __restrict__ noise_var_p,
    const float* __restrict__ noise_bias_p,
    float* __restrict__ out,
    int H, int W)
{
    __shared__ float tile[LTH][LTW];

    const float noise_var  = noise_var_p[0];
    const float noise_bias = noise_bias_p[0];

    const int b      = blockIdx.z;
    const int tile_y = blockIdx.y * TSY;
    const int tile_x = blockIdx.x * TSX;
    const int tx = threadIdx.x;
    const int ty = threadIdx.y;
    const int tid = ty * BDX + tx;

    const float* __restrict__ img = x + (size_t)b * H * W;

    const bool interior = (blockIdx.x > 0) && (blockIdx.x < gridDim.x - 1) &&
                          (blockIdx.y > 0) && (blockIdx.y < gridDim.y - 1);
    if (interior) {
        // Vectorized staging: 340 float4 chunks, linear chunk i -> tile[i/17][(i%17)*4].
        const float* gbase = img + (size_t)(tile_y - PAD) * W + (tile_x - PAD);
        {
            const int i = tid;                 // 0..255
            const int row = i / 17;
            const int cc  = i - row * 17;
            float4u v = *(const float4u*)(gbase + (size_t)row * W + cc * 4);
            *(float4u*)&tile[row][cc * 4] = v;   // 16B-aligned LDS write
        }
        if (tid < NCHUNK - 256) {              // 84 remaining chunks
            const int i = tid + 256;
            const int row = i / 17;
            const int cc  = i - row * 17;
            float4u v = *(const float4u*)(gbase + (size_t)row * W + cc * 4);
            *(float4u*)&tile[row][cc * 4] = v;
        }
    } else {
        // Edge blocks: scalar bounds-checked staging (zero pad).
        for (int i = tid; i < LTH * LTW; i += BDX * BDY) {
            const int ly = i / LTW;
            const int lx = i - ly * LTW;
            const int gy = tile_y + ly - PAD;
            const int gx = tile_x + lx - PAD;
            float v = 0.0f;
            if (gy >= 0 && gy < H && gx >= 0 && gx < W)
                v = img[(size_t)gy * W + gx];
            tile[ly][lx] = v;
        }
    }
    __syncthreads();

    // Load fragments as two float4 per row (cols tx*4 .. tx*4+7).
    v4f A[5], D[5];
    #pragma unroll
    for (int r = 0; r < 5; ++r) {
        A[r] = *(const v4f*)&tile[ty + r][tx * PX];
        D[r] = *(const v4f*)&tile[ty + r][tx * PX + 4];
    }

    // Column sums / sums of squares on packed vectors (v_pk_add/fma_f32).
    v4f SA = ((A[0] + A[1]) + (A[2] + A[3])) + A[4];
    v4f SD = ((D[0] + D[1]) + (D[2] + D[3])) + D[4];
    v4f QA = A[0] * A[0];
    v4f QD = D[0] * D[0];
    #pragma unroll
    for (int r = 1; r < 5; ++r) { QA = A[r] * A[r] + QA; QD = D[r] * D[r] + QD; }

    const float s8[8] = {SA.x, SA.y, SA.z, SA.w, SD.x, SD.y, SD.z, SD.w};
    const float q8[8] = {QA.x, QA.y, QA.z, QA.w, QD.x, QD.y, QD.z, QD.w};

    float sum5[PX], sq5[PX];
    sum5[0] = ((s8[0] + s8[1]) + (s8[2] + s8[3])) + s8[4];
    sq5[0]  = ((q8[0] + q8[1]) + (q8[2] + q8[3])) + q8[4];
    #pragma unroll
    for (int p = 1; p < PX; ++p) {
        sum5[p] = sum5[p - 1] - s8[p - 1] + s8[p + 4];
        sq5[p]  = sq5[p - 1]  - q8[p - 1] + q8[p + 4];
    }

    // Center pixels (raw values, col p+2 row 2).
    const float center[PX] = {A[2].z, A[2].w, D[2].x, D[2].y};

    // Unpack to 8 columns and sort each column (15-op network w/ min3/max3/med3).
    float c[8][5];
    #pragma unroll
    for (int r = 0; r < 5; ++r) {
        c[0][r] = A[r].x; c[1][r] = A[r].y; c[2][r] = A[r].z; c[3][r] = A[r].w;
        c[4][r] = D[r].x; c[5][r] = D[r].y; c[6][r] = D[r].z; c[7][r] = D[r].w;
    }
    #pragma unroll
    for (int k = 0; k < 8; ++k) {
        const float a1 = fminf(c[k][0], c[k][1]), a2 = fmaxf(c[k][0], c[k][1]);
        const float b1 = fminf(c[k][2], c[k][3]), b2 = fmaxf(c[k][2], c[k][3]);
        const float cc = c[k][4];
        const float t1 = fminf(a2, b2), t3 = fmaxf(a1, b1);
        const float M  = fmaxf(a2, b2), m  = fminf(a1, b1);
        c[k][0] = fminf(m, cc);                       // min of 5
        c[k][4] = fmaxf(M, cc);                       // max of 5
        c[k][2] = med3f(t1, t3, cc);                  // median of 5
        c[k][3] = max3f(t1, fminf(cc, M), t3);        // 2nd largest
        c[k][1] = min3f(t3, fmaxf(cc, m), t1);        // 2nd smallest
    }

    float4 res;
    float* resp = (float*)&res;

    #pragma unroll
    for (int p = 0; p < PX; ++p) {
        float A1, A2, B1, B2, B3, C1, C2, C3, D1, D2, D3, E1, E2;
        // row 0 (column minima): need sorted pos 3,4 (2nd-largest, largest)
        {
            const float a1 = fminf(c[p][0], c[p+1][0]), a2 = fmaxf(c[p][0], c[p+1][0]);
            const float b1 = fminf(c[p+2][0], c[p+3][0]), b2 = fmaxf(c[p+2][0], c[p+3][0]);
            const float cc = c[p+4][0];
            const float M = fmaxf(a2, b2), t1 = fminf(a2, b2), t3 = fmaxf(a1, b1);
            A2 = fmaxf(M, cc);
            A1 = max3f(t1, fminf(cc, M), t3);
        }
        // row 1: need pos 2,3,4 (median, 2nd-largest, largest)
        {
            const float a1 = fminf(c[p][1], c[p+1][1]), a2 = fmaxf(c[p][1], c[p+1][1]);
            const float b1 = fminf(c[p+2][1], c[p+3][1]), b2 = fmaxf(c[p+2][1], c[p+3][1]);
            const float cc = c[p+4][1];
            const float M = fmaxf(a2, b2), t1 = fminf(a2, b2), t3 = fmaxf(a1, b1);
            B3 = fmaxf(M, cc);
            B2 = max3f(t1, fminf(cc, M), t3);
            B1 = med3f(t1, t3, cc);
        }
        // row 2: need pos 1,2,3
        {
            const float a1 = fminf(c[p][2], c[p+1][2]), a2 = fmaxf(c[p][2], c[p+1][2]);
            const float b1 = fminf(c[p+2][2], c[p+3][2]), b2 = fmaxf(c[p+2][2], c[p+3][2]);
            const float cc = c[p+4][2];
            const float M = fmaxf(a2, b2), m = fminf(a1, b1);
            const float t1 = fminf(a2, b2), t3 = fmaxf(a1, b1);
            C2 = med3f(t1, t3, cc);
            C3 = max3f(t1, fminf(cc, M), t3);
            C1 = min3f(t3, fmaxf(cc, m), t1);
        }
        // row 3: need pos 0,1,2 (min, 2nd-smallest, median)
        {
            const float a1 = fminf(c[p][3], c[p+1][3]), a2 = fmaxf(c[p][3], c[p+1][3]);
            const float b1 = fminf(c[p+2][3], c[p+3][3]), b2 = fmaxf(c[p+2][3], c[p+3][3]);
            const float cc = c[p+4][3];
            const float m = fminf(a1, b1), t1 = fminf(a2, b2), t3 = fmaxf(a1, b1);
            D1 = fminf(m, cc);
            D2 = min3f(t3, fmaxf(cc, m), t1);
            D3 = med3f(t1, t3, cc);
        }
        // row 4 (column maxima): need pos 0,1 (min, 2nd-smallest)
        {
            const float a1 = fminf(c[p][4], c[p+1][4]), a2 = fmaxf(c[p][4], c[p+1][4]);
            const float b1 = fminf(c[p+2][4], c[p+3][4]), b2 = fmaxf(c[p+2][4], c[p+3][4]);
            const float cc = c[p+4][4];
            const float m = fminf(a1, b1), t1 = fminf(a2, b2), t3 = fmaxf(a1, b1);
            E1 = fminf(m, cc);
            E2 = min3f(t3, fmaxf(cc, m), t1);
        }

        // poset elimination: 13 candidates -> 9 (rank-counted, provably safe)
        const float mn1 = fminf(B3, D3);
        const float mn2 = fminf(C3, E2);
        const float mx1 = fmaxf(B1, D1);
        const float mx2 = fmaxf(A1, C1);

        float q0 = mx2, q1 = A2, q2 = B2, q3 = C2, q4 = D2,
              q5 = E1, q6 = mx1, q7 = mn1, q8 = mn2;
        MED9(q0, q1, q2, q3, q4, q5, q6, q7, q8);
        const float mid = q4;

        // unbiased variance from shared column sums
        const float sum = sum5[p];
        const float sq  = sq5[p];
        const float mean = sum * (1.0f / 25.0f);
        float var = (sq - sum * mean) * (1.0f / 24.0f);
        var = fmaxf(var, 0.0f);

        const float xc = center[p];
        const float rr = __builtin_amdgcn_rcpf(var + 1e-10f);
        float y = xc - noise_var * rr * (xc - mid + noise_bias);
        resp[p] = fmaxf(y, 0.0f);
    }

    const int gy = tile_y + ty;
    const int gx = tile_x + tx * PX;
    *(float4*)&out[((size_t)b * H + gy) * W + gx] = res;
}

extern "C" void kernel_launch(void* const* d_in, const int* in_sizes, int n_in,
                              void* d_out, int out_size, void* d_ws, size_t ws_size,
                              hipStream_t stream)
{
    const float* x  = (const float*)d_in[0];
    const float* nv = (const float*)d_in[1];
    const float* nb = (const float*)d_in[2];
    float* out = (float*)d_out;

    const int H = 512, W = 512;
    const int B = in_sizes[0] / (H * W);   // 16 (C==1)

    dim3 block(BDX, BDY, 1);
    dim3 grid(W / TSX, H / TSY, B);
    denoise_median5_kernel<<<grid, block, 0, stream>>>(x, nv, nb, out, H, W);
}